// Round 5
// baseline (190.325 us; speedup 1.0000x reference)
//
#include <hip/hip_runtime.h>

#define HIDDEN 1024
#define SEQ 2048
#define NB 2
#define PSTRIDE 2052  // halfs per LDS score row: 2048 + 4 pad (bank-spread, 8B-aligned)
#define NT 16         // q-tiles per persistent block

typedef _Float16 half8 __attribute__((ext_vector_type(8)));
typedef _Float16 half4 __attribute__((ext_vector_type(4)));
typedef float f32x4 __attribute__((ext_vector_type(4)));

// ---------------- cast x fp32 -> fp16 ----------------
__global__ __launch_bounds__(256) void cast_x(const float* __restrict__ x,
                                              _Float16* __restrict__ xh, int n) {
    int i = (blockIdx.x * 256 + threadIdx.x) * 4;
    if (i < n) {
        float4 v = *(const float4*)(x + i);
        half4 h;
        h[0] = (_Float16)v.x; h[1] = (_Float16)v.y;
        h[2] = (_Float16)v.z; h[3] = (_Float16)v.w;
        *(half4*)(xh + i) = h;
    }
}

// ---------------- cast + transpose Wq: wt[n][k] = Wq[k][n] ----------------
__global__ __launch_bounds__(256) void cast_wt(const float* __restrict__ w,
                                               _Float16* __restrict__ wt) {
    __shared__ float tile[32][33];
    int bx = blockIdx.x * 32, by = blockIdx.y * 32;
    int tx = threadIdx.x, ty = threadIdx.y;   // (32, 8)
    #pragma unroll
    for (int i = 0; i < 32; i += 8)
        tile[ty + i][tx] = w[(by + ty + i) * HIDDEN + bx + tx];
    __syncthreads();
    #pragma unroll
    for (int i = 0; i < 32; i += 8)
        wt[(bx + ty + i) * HIDDEN + by + tx] = (_Float16)tile[tx][ty + i];
}

// ---------------- projection GEMM: Q = x @ Wq + bq  (fp16 in/out, fp32 acc) ----------------
__global__ __launch_bounds__(256) void proj_gemm(const _Float16* __restrict__ A,
                                                 const _Float16* __restrict__ Bt,
                                                 const float* __restrict__ bias,
                                                 _Float16* __restrict__ Q) {
    __shared__ _Float16 As[128][72];
    __shared__ _Float16 Bs[128][72];
    const int m0 = blockIdx.x * 128;
    const int n0 = blockIdx.y * 128;
    const int tid = threadIdx.x;
    const int w = tid >> 6, l = tid & 63;
    const int wm = w >> 1, wn = w & 1;           // 2x2 waves, each 64x64
    const int lrow = l & 15, lk = (l >> 4) * 8;

    f32x4 acc[4][4] = {};

    for (int k0 = 0; k0 < HIDDEN; k0 += 64) {
        __syncthreads();
        #pragma unroll
        for (int i = 0; i < 4; ++i) {
            int id = tid + i * 256;
            int r = id >> 3, c = id & 7;
            *(half8*)&As[r][c * 8] = *(const half8*)&A[(size_t)(m0 + r) * HIDDEN + k0 + c * 8];
        }
        #pragma unroll
        for (int i = 0; i < 4; ++i) {
            int id = tid + i * 256;
            int r = id >> 3, c = id & 7;
            *(half8*)&Bs[r][c * 8] = *(const half8*)&Bt[(size_t)(n0 + r) * HIDDEN + k0 + c * 8];
        }
        __syncthreads();
        #pragma unroll
        for (int kk = 0; kk < 64; kk += 32) {
            half8 af[4], bf[4];
            #pragma unroll
            for (int m = 0; m < 4; ++m)
                af[m] = *(const half8*)&As[wm * 64 + m * 16 + lrow][kk + lk];
            #pragma unroll
            for (int n = 0; n < 4; ++n)
                bf[n] = *(const half8*)&Bs[wn * 64 + n * 16 + lrow][kk + lk];
            #pragma unroll
            for (int m = 0; m < 4; ++m)
                #pragma unroll
                for (int n = 0; n < 4; ++n)
                    acc[m][n] = __builtin_amdgcn_mfma_f32_16x16x32_f16(af[m], bf[n], acc[m][n], 0, 0, 0);
        }
    }
    const int lr4 = (l >> 4) * 4, lc = l & 15;
    #pragma unroll
    for (int n = 0; n < 4; ++n) {
        int gcol = n0 + wn * 64 + n * 16 + lc;
        float b = bias[gcol];
        #pragma unroll
        for (int m = 0; m < 4; ++m) {
            #pragma unroll
            for (int r = 0; r < 4; ++r) {
                int grow = m0 + wm * 64 + m * 16 + lr4 + r;
                Q[(size_t)grow * HIDDEN + gcol] = (_Float16)(acc[m][n][r] + b);
            }
        }
    }
}

// ---------------- fused scores + softmax: persistent double-buffered pipeline ----------------
// 256 blocks x 1024 thr (1/CU, 133 KB LDS). Block owns 16 consecutive 16-row
// q-tiles of one (b,h). Per iteration: nt-store tile t-1 from buf (t-1)&1,
// compute tile t into buf t&1, then lgkmcnt(0)-only barrier (stores stay in
// flight across the barrier -> compute hides under the HBM write drain).
// p = exp(e/8 - 8) cached fp16 (shift cancels in normalization).
__global__ __launch_bounds__(1024, 4) void scores_softmax(const _Float16* __restrict__ Qh,
                                                          float* __restrict__ out) {
    __shared__ __align__(16) _Float16 p[2][16][PSTRIDE];
    __shared__ float rsum_lds[2][16][16];   // [buf][compute-wave][q-row]

    // chunked XCD swizzle: raw%8 = XCD -> bid = (raw&7)*32 + raw>>3 gives each
    // XCD 32 consecutive bids = 4 bh slices (1 MB K working set per L2).
    const int raw = blockIdx.x;
    const int bid = (raw & 7) * 32 + (raw >> 3);
    const int bh = bid >> 3;           // 0..31
    const int qchunk = bid & 7;        // 0..7 : rows [qchunk*256, +256)
    const int b = bh >> 4, h = bh & 15;

    const int tid = threadIdx.x;
    const int w = tid >> 6;            // wave 0..15
    const int l = tid & 63;
    const int lq = l & 15, lg = l >> 4;
    const int hoff = h * 64;
    const _Float16* qbase = Qh + (size_t)b * SEQ * HIDDEN;
    // K fragment base (A operand): lane&15 = k-row within 16-frag, lg*8 = d-off
    const _Float16* kbase = qbase + (size_t)lq * HIDDEN + hoff + lg * 8;
    const size_t outbase = (size_t)(b * 16 + h) * SEQ * SEQ;

    for (int t = 0; t <= NT; ++t) {
        const int buf = t & 1, pbuf = buf ^ 1;

        // ---- STORE tile t-1 from pbuf: wave w stores q-row w ----
        if (t > 0) {
            float rs = 0.f;
            #pragma unroll
            for (int cw = 0; cw < 16; ++cw) rs += rsum_lds[pbuf][cw][w];
            const float rinv = 1.0f / rs;
            float* orow = out + outbase + (size_t)(qchunk * 256 + (t - 1) * 16 + w) * SEQ;
            #pragma unroll
            for (int i = 0; i < 8; ++i) {
                half4 hv = *(const half4*)&p[pbuf][w][i * 256 + l * 4];
                f32x4 v;
                v[0] = (float)hv[0] * rinv; v[1] = (float)hv[1] * rinv;
                v[2] = (float)hv[2] * rinv; v[3] = (float)hv[3] * rinv;
                __builtin_nontemporal_store(v, (f32x4*)(orow + i * 256 + l * 4));
            }
        }

        // ---- COMPUTE tile t into buf: wave w covers k in [w*128, w*128+128) ----
        if (t < NT) {
            const int q0 = qchunk * 256 + t * 16;
            const _Float16* qp = qbase + (size_t)(q0 + lq) * HIDDEN + hoff + lg * 8;
            const half8 bq0 = *(const half8*)qp;
            const half8 bq1 = *(const half8*)(qp + 32);

            // all 8 K-frags issued upfront (MLP; ~64 VGPR)
            half8 ka[8], kb[8];
            #pragma unroll
            for (int s = 0; s < 8; ++s) {
                const _Float16* a = kbase + (size_t)(w * 128 + s * 16) * HIDDEN;
                ka[s] = *(const half8*)a;
                kb[s] = *(const half8*)(a + 32);
            }
            float rsum = 0.f;
            #pragma unroll
            for (int s = 0; s < 8; ++s) {
                f32x4 acc = {};
                acc = __builtin_amdgcn_mfma_f32_16x16x32_f16(ka[s], bq0, acc, 0, 0, 0);
                acc = __builtin_amdgcn_mfma_f32_16x16x32_f16(kb[s], bq1, acc, 0, 0, 0);
                // C layout: col(q)=lane&15, row(k)=lg*4+reg
                float e0 = __expf(fmaf(acc[0], 0.125f, -8.0f));
                float e1 = __expf(fmaf(acc[1], 0.125f, -8.0f));
                float e2 = __expf(fmaf(acc[2], 0.125f, -8.0f));
                float e3 = __expf(fmaf(acc[3], 0.125f, -8.0f));
                rsum += (e0 + e1) + (e2 + e3);
                half4 hv;
                hv[0] = (_Float16)e0; hv[1] = (_Float16)e1;
                hv[2] = (_Float16)e2; hv[3] = (_Float16)e3;
                *(half4*)&p[buf][lq][w * 128 + s * 16 + lg * 4] = hv;
            }
            rsum += __shfl_xor(rsum, 16);
            rsum += __shfl_xor(rsum, 32);
            if (l < 16) rsum_lds[buf][w][l] = rsum;
        }

        // LDS-only barrier: nt stores stay in flight across iterations.
        asm volatile("s_waitcnt lgkmcnt(0)" ::: "memory");
        __builtin_amdgcn_s_barrier();
    }
}

extern "C" void kernel_launch(void* const* d_in, const int* in_sizes, int n_in,
                              void* d_out, int out_size, void* d_ws, size_t ws_size,
                              hipStream_t stream) {
    const float* x  = (const float*)d_in[0];   // [2,2048,1024]
    const float* Wq = (const float*)d_in[1];   // [1024,1024]
    const float* bq = (const float*)d_in[2];   // [1024]
    float* out = (float*)d_out;                // [2,16,2048,2048]

    _Float16* xh = (_Float16*)d_ws;                    // 8 MB
    _Float16* qh = xh + (size_t)4 * 1024 * 1024;       // 8 MB
    _Float16* wt = qh + (size_t)4 * 1024 * 1024;       // 2 MB

    const int nx = NB * SEQ * HIDDEN;  // 4194304
    cast_x<<<nx / (256 * 4), 256, 0, stream>>>(x, xh, nx);
    cast_wt<<<dim3(32, 32), dim3(32, 8), 0, stream>>>(Wq, wt);
    proj_gemm<<<dim3(NB * SEQ / 128, HIDDEN / 128), 256, 0, stream>>>(xh, wt, bq, qh);
    scores_softmax<<<256, 1024, 0, stream>>>(qh, out);
}